// Round 3
// baseline (1263.372 us; speedup 1.0000x reference)
//
#include <hip/hip_runtime.h>
#include <hip/hip_bf16.h>

// Problem constants (fixed by setup_inputs)
#define BB_  64
#define TT_  512
#define FF_  1024
#define HH_  31
#define GG_  124   // 4*H
#define FUT_ 16
#define TTOT_ 528  // T + future
#define OUT_ROW_ ((size_t)TTOT_ * FF_)   // per-batch stride in output

__device__ __forceinline__ float fsig(float x) { return 1.0f / (1.0f + __expf(-x)); }
__device__ __forceinline__ float ftanh_(float x) { return 1.0f - 2.0f / (1.0f + __expf(2.0f * x)); }

// ---------------- K0: transpose W_lin [1024][31] -> WT [31][1024] ----------------
__global__ void k0_prep(const float* __restrict__ Wlin, float* __restrict__ WT) {
    int i = blockIdx.x * 256 + threadIdx.x;   // 124*256 = 31744 = 1024*31 exactly
    int j = i / 31;
    int k = i - j * 31;
    WT[k * 1024 + j] = Wlin[i];
}

// ---------------- K1: pregate GEMM: pre1[t][b][g] = x[b][t] . Wih1[g] + b1 ----------------
// One block per t; M-tile = 64 (all batches), N = 124 (pad 128), K = 1024 in chunks of 32.
__global__ __launch_bounds__(256) void k1_pregate(
    const float* __restrict__ X,      // [B][T][F] fp32
    const float* __restrict__ Wih1,   // [G][F] fp32
    const float* __restrict__ bih1,
    const float* __restrict__ bhh1,
    float* __restrict__ pre1)         // [T][B][128]
{
    __shared__ __align__(16) float xs[32][64];    // [k][row]
    __shared__ __align__(16) float ws[32][128];   // [k][col]
    const int tid  = threadIdx.x;
    const int t    = blockIdx.x;
    const int tcol = tid & 31, trow = tid >> 5;
    const int c0 = tcol * 4, r0 = trow * 8;

    float4 acc[8];
#pragma unroll
    for (int r = 0; r < 8; r++) acc[r] = make_float4(0.f, 0.f, 0.f, 0.f);

    for (int kc = 0; kc < 32; ++kc) {
        const int k0 = kc * 32;
        // stage x: 64 rows x 32 k
#pragma unroll
        for (int p = 0; p < 2; p++) {
            int i = tid + p * 256;
            int r = i >> 3, f = i & 7;
            float4 v = *(const float4*)(X + (size_t)r * TT_ * FF_ + (size_t)t * FF_ + k0 + f * 4);
            xs[f * 4 + 0][r] = v.x; xs[f * 4 + 1][r] = v.y;
            xs[f * 4 + 2][r] = v.z; xs[f * 4 + 3][r] = v.w;
        }
        // stage W: 124 rows x 32 k (transposed), zero-pad cols 124..127
#pragma unroll
        for (int p = 0; p < 4; p++) {
            int i = tid + p * 256;
            int g = i >> 3, f = i & 7;
            float4 v = make_float4(0.f, 0.f, 0.f, 0.f);
            if (g < GG_) v = *(const float4*)(Wih1 + (size_t)g * FF_ + k0 + f * 4);
            ws[f * 4 + 0][g] = v.x; ws[f * 4 + 1][g] = v.y;
            ws[f * 4 + 2][g] = v.z; ws[f * 4 + 3][g] = v.w;
        }
        __syncthreads();
#pragma unroll
        for (int k = 0; k < 32; k++) {
            float4 wv = *(const float4*)&ws[k][c0];
            float4 xa = *(const float4*)&xs[k][r0];
            float4 xb = *(const float4*)&xs[k][r0 + 4];
            float rx[8] = {xa.x, xa.y, xa.z, xa.w, xb.x, xb.y, xb.z, xb.w};
#pragma unroll
            for (int r = 0; r < 8; r++) {
                acc[r].x += rx[r] * wv.x; acc[r].y += rx[r] * wv.y;
                acc[r].z += rx[r] * wv.z; acc[r].w += rx[r] * wv.w;
            }
        }
        __syncthreads();
    }
    // bias + store
    float bias[4];
#pragma unroll
    for (int cc = 0; cc < 4; cc++) {
        int c = c0 + cc;
        bias[cc] = (c < GG_) ? (bih1[c] + bhh1[c]) : 0.0f;
    }
#pragma unroll
    for (int r = 0; r < 8; r++) {
        int m = t * 64 + r0 + r;
        float4 o = acc[r];
        o.x += bias[0]; o.y += bias[1]; o.z += bias[2]; o.w += bias[3];
        *(float4*)(pre1 + (size_t)m * 128 + c0) = o;
    }
}

// ---------------- K2: sequential recurrence, one block per batch ----------------
__global__ __launch_bounds__(128, 1) void k2_recur(
    const float* __restrict__ pre1,   // [T][B][128]
    const float* __restrict__ Whh1,   // [G][H]
    const float* __restrict__ Wih2,   // [G][H]
    const float* __restrict__ Whh2,   // [G][H]
    const float* __restrict__ bih1, const float* __restrict__ bhh1,
    const float* __restrict__ bih2, const float* __restrict__ bhh2,
    const float* __restrict__ Wih1,   // [G][F]   (future phase)
    const float* __restrict__ WTlin,  // [31][1024]
    const float* __restrict__ blin,   // [1024]
    float* __restrict__ h2a,          // [T*B][32]
    float* __restrict__ out)          // [B][528][1024] fp32
{
    __shared__ __align__(16) float h1s[32];
    __shared__ __align__(16) float h2s[32];
    __shared__ __align__(16) float gr[128];
    __shared__ __align__(16) float xb[1024];
    const int g  = threadIdx.x;
    const int bb = blockIdx.x;

    float w1[32], wi2[32], wh2[32];
    float b1c = 0.0f, b2c = 0.0f;
    if (g < GG_) {
#pragma unroll
        for (int k = 0; k < 31; k++) {
            w1[k]  = Whh1[g * 31 + k];
            wi2[k] = Wih2[g * 31 + k];
            wh2[k] = Whh2[g * 31 + k];
        }
        w1[31] = wi2[31] = wh2[31] = 0.0f;
        b1c = bih1[g] + bhh1[g];
        b2c = bih2[g] + bhh2[g];
    } else {
#pragma unroll
        for (int k = 0; k < 32; k++) { w1[k] = wi2[k] = wh2[k] = 0.0f; }
    }
    if (g < 32) { h1s[g] = 0.0f; h2s[g] = 0.0f; }
    float c1 = 0.0f, c2 = 0.0f;
    __syncthreads();

    float pref = (g < GG_) ? pre1[(size_t)bb * 128 + g] : 0.0f;

    for (int t = 0; t < TT_; t++) {
        float cur = pref;
        if (t + 1 < TT_ && g < GG_) pref = pre1[((size_t)(t + 1) * 64 + bb) * 128 + g];
        // phase A: layer-1 gates
        {
            float a = cur;
            const float4* h1v = (const float4*)h1s;
            float4 hq[8];
#pragma unroll
            for (int q = 0; q < 8; q++) hq[q] = h1v[q];
            const float* hf = (const float*)hq;
#pragma unroll
            for (int k = 0; k < 32; k++) a += w1[k] * hf[k];
            if (g < GG_) gr[g] = a;
        }
        __syncthreads();
        // phase B: layer-1 state update
        if (g < HH_) {
            float ii = fsig(gr[g]);
            float ff = fsig(gr[g + 31]);
            float gg = ftanh_(gr[g + 62]);
            float oo = fsig(gr[g + 93]);
            c1 = ff * c1 + ii * gg;
            h1s[g] = oo * ftanh_(c1);
        }
        __syncthreads();
        // phase C: layer-2 gates
        {
            const float4* h1v = (const float4*)h1s;
            const float4* h2v = (const float4*)h2s;
            float4 aq[8], bq[8];
#pragma unroll
            for (int q = 0; q < 8; q++) { aq[q] = h1v[q]; bq[q] = h2v[q]; }
            const float* af = (const float*)aq;
            const float* bf = (const float*)bq;
            float a = b2c;
#pragma unroll
            for (int k = 0; k < 32; k++) a += wi2[k] * af[k] + wh2[k] * bf[k];
            if (g < GG_) gr[g] = a;
        }
        __syncthreads();
        // phase D: layer-2 state update + save h2
        if (g < HH_) {
            float ii = fsig(gr[g]);
            float ff = fsig(gr[g + 31]);
            float gg = ftanh_(gr[g + 62]);
            float oo = fsig(gr[g + 93]);
            c2 = ff * c2 + ii * gg;
            float h2 = oo * ftanh_(c2);
            h2s[g] = h2;
            h2a[((size_t)t * 64 + bb) * 32 + g] = h2;
        }
        __syncthreads();
    }

    // ---- autoregressive future phase ----
    for (int s = 0; s <= FUT_; ++s) {
        // out(511+s) from current h2s -> xb; store for s>0
        {
            const float4* h2v = (const float4*)h2s;
            float4 hq[8];
#pragma unroll
            for (int q = 0; q < 8; q++) hq[q] = h2v[q];
            const float* hf = (const float*)hq;
#pragma unroll
            for (int m = 0; m < 8; m++) {
                int j = g + m * 128;
                float a = blin[j];
#pragma unroll
                for (int k = 0; k < 31; k++) a += hf[k] * WTlin[k * 1024 + j];
                xb[j] = a;
                if (s > 0) out[(size_t)bb * OUT_ROW_ + (size_t)(511 + s) * FF_ + j] = a;
            }
        }
        if (s == FUT_) break;
        __syncthreads();
        // layer-1 gates with x = xb (1024-dot, per-lane row streaming of Wih1)
        {
            float a = b1c;
            if (g < GG_) {
                const float4* wr = (const float4*)(Wih1 + (size_t)g * FF_);
                const float4* xv = (const float4*)xb;
#pragma unroll 8
                for (int q = 0; q < 256; q++) {
                    float4 w = wr[q]; float4 x4 = xv[q];
                    a += w.x * x4.x + w.y * x4.y + w.z * x4.z + w.w * x4.w;
                }
            }
            const float4* h1v = (const float4*)h1s;
            float4 hq[8];
#pragma unroll
            for (int q = 0; q < 8; q++) hq[q] = h1v[q];
            const float* hf = (const float*)hq;
#pragma unroll
            for (int k = 0; k < 32; k++) a += w1[k] * hf[k];
            if (g < GG_) gr[g] = a;
        }
        __syncthreads();
        if (g < HH_) {
            float ii = fsig(gr[g]);
            float ff = fsig(gr[g + 31]);
            float gg = ftanh_(gr[g + 62]);
            float oo = fsig(gr[g + 93]);
            c1 = ff * c1 + ii * gg;
            h1s[g] = oo * ftanh_(c1);
        }
        __syncthreads();
        {
            const float4* h1v = (const float4*)h1s;
            const float4* h2v = (const float4*)h2s;
            float4 aq[8], bq[8];
#pragma unroll
            for (int q = 0; q < 8; q++) { aq[q] = h1v[q]; bq[q] = h2v[q]; }
            const float* af = (const float*)aq;
            const float* bf = (const float*)bq;
            float a = b2c;
#pragma unroll
            for (int k = 0; k < 32; k++) a += wi2[k] * af[k] + wh2[k] * bf[k];
            if (g < GG_) gr[g] = a;
        }
        __syncthreads();
        if (g < HH_) {
            float ii = fsig(gr[g]);
            float ff = fsig(gr[g + 31]);
            float gg = ftanh_(gr[g + 62]);
            float oo = fsig(gr[g + 93]);
            c2 = ff * c2 + ii * gg;
            h2s[g] = oo * ftanh_(c2);
        }
        __syncthreads();
    }
}

// ---------------- K3: output linear for teacher steps: out[b][t][:] = h2 . WT + b ----------------
__global__ __launch_bounds__(256) void k3_outlin(
    const float* __restrict__ h2a,   // [T*B][32]
    const float* __restrict__ WT,    // [31][1024]
    const float* __restrict__ blin,  // [1024]
    float* __restrict__ out)         // fp32
{
    __shared__ __align__(16) float hl[16][32];
    const int tid = threadIdx.x;
    const int m0  = blockIdx.x * 16;
#pragma unroll
    for (int p = 0; p < 2; p++) {
        int i = tid + p * 256;
        int r = i >> 5, k = i & 31;
        hl[r][k] = h2a[(size_t)(m0 + r) * 32 + k];
    }
    __syncthreads();
    const int c0 = tid * 4;
    float4 bl = *(const float4*)(blin + c0);
    float4 acc[16];
#pragma unroll
    for (int r = 0; r < 16; r++) acc[r] = bl;
    for (int k = 0; k < 31; k++) {
        float4 wv = *(const float4*)(WT + k * 1024 + c0);
#pragma unroll
        for (int r = 0; r < 16; r++) {
            float h = hl[r][k];
            acc[r].x += h * wv.x; acc[r].y += h * wv.y;
            acc[r].z += h * wv.z; acc[r].w += h * wv.w;
        }
    }
    const int t  = m0 >> 6;
    const int b0 = m0 & 63;
#pragma unroll
    for (int r = 0; r < 16; r++) {
        int b = b0 + r;
        *(float4*)(out + (size_t)b * OUT_ROW_ + (size_t)t * FF_ + c0) = acc[r];
    }
}

extern "C" void kernel_launch(void* const* d_in, const int* in_sizes, int n_in,
                              void* d_out, int out_size, void* d_ws, size_t ws_size,
                              hipStream_t stream) {
    (void)in_sizes; (void)n_in; (void)out_size; (void)ws_size;
    const float* X    = (const float*)d_in[0];
    const float* Wih1 = (const float*)d_in[1];
    const float* Whh1 = (const float*)d_in[2];
    const float* bih1 = (const float*)d_in[3];
    const float* bhh1 = (const float*)d_in[4];
    const float* Wih2 = (const float*)d_in[5];
    const float* Whh2 = (const float*)d_in[6];
    const float* bih2 = (const float*)d_in[7];
    const float* bhh2 = (const float*)d_in[8];
    const float* Wlin = (const float*)d_in[9];
    const float* blin = (const float*)d_in[10];
    // d_in[11] = future = 16 (constant for this problem)

    float* pre1 = (float*)d_ws;                          // 512*64*128 f32 = 16 MiB
    float* h2a  = pre1 + (size_t)TT_ * 64 * 128;         // 512*64*32 f32 = 4 MiB
    float* WT   = h2a + (size_t)TT_ * 64 * 32;           // 31*1024 f32
    float* out  = (float*)d_out;

    hipLaunchKernelGGL(k0_prep,    dim3(124),  dim3(256), 0, stream, Wlin, WT);
    hipLaunchKernelGGL(k1_pregate, dim3(TT_),  dim3(256), 0, stream, X, Wih1, bih1, bhh1, pre1);
    hipLaunchKernelGGL(k2_recur,   dim3(BB_),  dim3(128), 0, stream, pre1, Whh1, Wih2, Whh2,
                       bih1, bhh1, bih2, bhh2, Wih1, WT, blin, h2a, out);
    hipLaunchKernelGGL(k3_outlin,  dim3(2048), dim3(256), 0, stream, h2a, WT, blin, out);
}

// Round 4
// 1028.183 us; speedup vs baseline: 1.2287x; 1.2287x over previous
//
#include <hip/hip_runtime.h>
#include <hip/hip_bf16.h>

// Problem constants (fixed by setup_inputs)
#define BB_  64
#define TT_  512
#define FF_  1024
#define HH_  31
#define GG_  124   // 4*H
#define FUT_ 16
#define TTOT_ 528  // T + future
#define OUT_ROW_ ((size_t)TTOT_ * FF_)   // per-batch stride in output

// ---- workspace layout (float indices) ----
#define PRE1_OFF ((size_t)0)                              // [512][64][128]
#define H2A_OFF  (PRE1_OFF + (size_t)TT_*64*128)          // [528*64][32]
#define WT_OFF   (H2A_OFF  + (size_t)TTOT_*64*32)         // [31][1024]
#define MV_OFF   (WT_OFF   + 31*1024)                     // [124][32]

__device__ __forceinline__ float rdlane(float v, int k) {
    return __uint_as_float(__builtin_amdgcn_readlane(__float_as_uint(v), k));
}

// ---------------- K0: transpose W_lin [1024][31] -> WT [31][1024] ----------------
__global__ void k0_prep(const float* __restrict__ Wlin, float* __restrict__ WT) {
    int i = blockIdx.x * 256 + threadIdx.x;   // 124*256 = 31744 = 1024*31 exactly
    int j = i / 31;
    int k = i - j * 31;
    WT[k * 1024 + j] = Wlin[i];
}

// ---------------- K0b: Mv[g][k] = sum_j Wih1[g][j]*Wlin[j][k]  (k=31 -> blin) ----------------
__global__ __launch_bounds__(64) void k0b_mv(
    const float* __restrict__ Wih1, const float* __restrict__ Wlin,
    const float* __restrict__ blin, float* __restrict__ Mv)
{
    int i = blockIdx.x * 64 + threadIdx.x;   // 62*64 = 3968 = 124*32
    int g = i >> 5, k = i & 31;
    const float* wr = Wih1 + (size_t)g * FF_;
    float acc = 0.0f;
    if (k < 31) {
#pragma unroll 8
        for (int j = 0; j < FF_; j++) acc += wr[j] * Wlin[j * 31 + k];
    } else {
#pragma unroll 8
        for (int j = 0; j < FF_; j++) acc += wr[j] * blin[j];
    }
    Mv[i] = acc;
}

// ---------------- K1: pregate GEMM: pre1[t][b][g] = x[b][t] . Wih1[g] + b1 ----------------
__global__ __launch_bounds__(256) void k1_pregate(
    const float* __restrict__ X,      // [B][T][F] fp32
    const float* __restrict__ Wih1,   // [G][F] fp32
    const float* __restrict__ bih1,
    const float* __restrict__ bhh1,
    float* __restrict__ pre1)         // [T][B][128]
{
    __shared__ __align__(16) float xs[32][64];    // [k][row]
    __shared__ __align__(16) float ws[32][128];   // [k][col]
    const int tid  = threadIdx.x;
    const int t    = blockIdx.x;
    const int tcol = tid & 31, trow = tid >> 5;
    const int c0 = tcol * 4, r0 = trow * 8;

    float4 acc[8];
#pragma unroll
    for (int r = 0; r < 8; r++) acc[r] = make_float4(0.f, 0.f, 0.f, 0.f);

    for (int kc = 0; kc < 32; ++kc) {
        const int k0 = kc * 32;
#pragma unroll
        for (int p = 0; p < 2; p++) {
            int i = tid + p * 256;
            int r = i >> 3, f = i & 7;
            float4 v = *(const float4*)(X + (size_t)r * TT_ * FF_ + (size_t)t * FF_ + k0 + f * 4);
            xs[f * 4 + 0][r] = v.x; xs[f * 4 + 1][r] = v.y;
            xs[f * 4 + 2][r] = v.z; xs[f * 4 + 3][r] = v.w;
        }
#pragma unroll
        for (int p = 0; p < 4; p++) {
            int i = tid + p * 256;
            int g = i >> 3, f = i & 7;
            float4 v = make_float4(0.f, 0.f, 0.f, 0.f);
            if (g < GG_) v = *(const float4*)(Wih1 + (size_t)g * FF_ + k0 + f * 4);
            ws[f * 4 + 0][g] = v.x; ws[f * 4 + 1][g] = v.y;
            ws[f * 4 + 2][g] = v.z; ws[f * 4 + 3][g] = v.w;
        }
        __syncthreads();
#pragma unroll
        for (int k = 0; k < 32; k++) {
            float4 wv = *(const float4*)&ws[k][c0];
            float4 xa = *(const float4*)&xs[k][r0];
            float4 xb = *(const float4*)&xs[k][r0 + 4];
            float rx[8] = {xa.x, xa.y, xa.z, xa.w, xb.x, xb.y, xb.z, xb.w};
#pragma unroll
            for (int r = 0; r < 8; r++) {
                acc[r].x += rx[r] * wv.x; acc[r].y += rx[r] * wv.y;
                acc[r].z += rx[r] * wv.z; acc[r].w += rx[r] * wv.w;
            }
        }
        __syncthreads();
    }
    float bias[4];
#pragma unroll
    for (int cc = 0; cc < 4; cc++) {
        int c = c0 + cc;
        bias[cc] = (c < GG_) ? (bih1[c] + bhh1[c]) : 0.0f;
    }
#pragma unroll
    for (int r = 0; r < 8; r++) {
        int m = t * 64 + r0 + r;
        float4 o = acc[r];
        o.x += bias[0]; o.y += bias[1]; o.z += bias[2]; o.w += bias[3];
        *(float4*)(pre1 + (size_t)m * 128 + c0) = o;
    }
}

// ---------------- K2: sequential recurrence, ONE WAVE per batch, barrier-free ----------------
// Lane L owns gates L and L+64 (gate order i:0-30, f:31-61, g:62-92, o:93-123).
// Lane j (j<31) owns state h1[j], c1[j], h2[j], c2[j].
__global__ __launch_bounds__(64, 1) void k2_recur(
    const float* __restrict__ pre1,   // [T][B][128]  (bias already folded in)
    const float* __restrict__ Whh1,   // [G][H]
    const float* __restrict__ Wih2,   // [G][H]
    const float* __restrict__ Whh2,   // [G][H]
    const float* __restrict__ bih1, const float* __restrict__ bhh1,
    const float* __restrict__ bih2, const float* __restrict__ bhh2,
    const float* __restrict__ Mv,     // [124][32]  (M | v)
    float* __restrict__ h2a)          // [528*64][32]
{
    const int L  = threadIdx.x;       // 0..63
    const int bb = blockIdx.x;
    const int g0 = L;
    const int g1 = L + 64;
    const bool v2 = (g1 < GG_);       // L < 60

    // recurrent weights in registers: rows g0 and g1 of each [124][31] matrix
    float w1a[31],  w1b[31],  wi2a[31], wi2b[31], wh2a[31], wh2b[31];
#pragma unroll
    for (int k = 0; k < 31; k++) {
        w1a[k]  = Whh1[g0 * 31 + k];
        wi2a[k] = Wih2[g0 * 31 + k];
        wh2a[k] = Whh2[g0 * 31 + k];
        w1b[k]  = v2 ? Whh1[g1 * 31 + k] : 0.0f;
        wi2b[k] = v2 ? Wih2[g1 * 31 + k] : 0.0f;
        wh2b[k] = v2 ? Whh2[g1 * 31 + k] : 0.0f;
    }
    const float b1c0 = bih1[g0] + bhh1[g0];
    const float b1c1 = v2 ? (bih1[g1] + bhh1[g1]) : 0.0f;
    const float b2c0 = bih2[g0] + bhh2[g0];
    const float b2c1 = v2 ? (bih2[g1] + bhh2[g1]) : 0.0f;

    float hv1 = 0.0f, cv1 = 0.0f, hv2 = 0.0f, cv2 = 0.0f;

    // gather source lanes (dest lane j<31 pulls its f,g,o gates)
    const int f_src  = L + 31;
    const int gA_src = L + 62;   // act0 source, valid dest L<2
    const int gB_src = L - 2;    // act1 source, valid dest L>=2
    const int o_src  = L + 29;

    // prefetch first pregate
    float p0 = pre1[(size_t)bb * 128 + L];
    float p1 = pre1[(size_t)bb * 128 + L + 64];

    for (int t = 0; t < TT_; t++) {
        const float cur0 = p0, cur1 = p1;
        if (t + 1 < TT_) {
            size_t o = ((size_t)(t + 1) * 64 + bb) * 128;
            p0 = pre1[o + L];
            p1 = pre1[o + L + 64];
        }
        // ---- layer 1 gates ----
        float a0 = cur0, a1 = cur1;
#pragma unroll
        for (int k = 0; k < 31; k++) {
            float hk = rdlane(hv1, k);
            a0 += w1a[k] * hk;
            a1 += w1b[k] * hk;
        }
        // activations: act0 = L<62 ? sig(a0) : tanh(a0); act1 = L<29 ? tanh(a1) : sig(a1)
        {
            float z0 = (L < 62) ? a0 : (2.0f * a0);
            float s0 = 1.0f / (1.0f + __expf(-z0));
            float act0 = (L < 62) ? s0 : (2.0f * s0 - 1.0f);
            float z1 = (L < 29) ? (2.0f * a1) : a1;
            float s1 = 1.0f / (1.0f + __expf(-z1));
            float act1 = (L < 29) ? (2.0f * s1 - 1.0f) : s1;
            // gather to state-owner lanes
            float ig = act0;                      // lane j<31 holds i_j locally
            float fg = __shfl(act0, f_src);
            float gA = __shfl(act0, gA_src);
            float gB = __shfl(act1, gB_src);
            float gg = (L < 2) ? gA : gB;
            float og = __shfl(act1, o_src);
            cv1 = fg * cv1 + ig * gg;
            float e = __expf(-2.0f * cv1);
            hv1 = og * (2.0f / (1.0f + e) - 1.0f);
        }
        // ---- layer 2 gates ----
        a0 = b2c0; a1 = b2c1;
#pragma unroll
        for (int k = 0; k < 31; k++) {
            float h1k = rdlane(hv1, k);
            float h2k = rdlane(hv2, k);
            a0 += wi2a[k] * h1k + wh2a[k] * h2k;
            a1 += wi2b[k] * h1k + wh2b[k] * h2k;
        }
        {
            float z0 = (L < 62) ? a0 : (2.0f * a0);
            float s0 = 1.0f / (1.0f + __expf(-z0));
            float act0 = (L < 62) ? s0 : (2.0f * s0 - 1.0f);
            float z1 = (L < 29) ? (2.0f * a1) : a1;
            float s1 = 1.0f / (1.0f + __expf(-z1));
            float act1 = (L < 29) ? (2.0f * s1 - 1.0f) : s1;
            float ig = act0;
            float fg = __shfl(act0, f_src);
            float gA = __shfl(act0, gA_src);
            float gB = __shfl(act1, gB_src);
            float gg = (L < 2) ? gA : gB;
            float og = __shfl(act1, o_src);
            cv2 = fg * cv2 + ig * gg;
            float e = __expf(-2.0f * cv2);
            hv2 = og * (2.0f / (1.0f + e) - 1.0f);
        }
        if (L < HH_) h2a[((size_t)t * 64 + bb) * 32 + L] = hv2;
    }

    // ---- autoregressive future: pregate = M*h2 + v + b1 (1024-dot eliminated) ----
    float m0r[32], m1r[32];
#pragma unroll
    for (int k = 0; k < 32; k++) {
        m0r[k] = Mv[g0 * 32 + k];
        m1r[k] = v2 ? Mv[g1 * 32 + k] : 0.0f;
    }
    for (int s = 0; s < FUT_; s++) {
        float a0 = b1c0 + m0r[31];   // + v[g0]
        float a1 = b1c1 + m1r[31];
#pragma unroll
        for (int k = 0; k < 31; k++) {
            float h2k = rdlane(hv2, k);
            a0 += m0r[k] * h2k;
            a1 += m1r[k] * h2k;
        }
#pragma unroll
        for (int k = 0; k < 31; k++) {
            float hk = rdlane(hv1, k);
            a0 += w1a[k] * hk;
            a1 += w1b[k] * hk;
        }
        {
            float z0 = (L < 62) ? a0 : (2.0f * a0);
            float s0 = 1.0f / (1.0f + __expf(-z0));
            float act0 = (L < 62) ? s0 : (2.0f * s0 - 1.0f);
            float z1 = (L < 29) ? (2.0f * a1) : a1;
            float s1 = 1.0f / (1.0f + __expf(-z1));
            float act1 = (L < 29) ? (2.0f * s1 - 1.0f) : s1;
            float ig = act0;
            float fg = __shfl(act0, f_src);
            float gA = __shfl(act0, gA_src);
            float gB = __shfl(act1, gB_src);
            float gg = (L < 2) ? gA : gB;
            float og = __shfl(act1, o_src);
            cv1 = fg * cv1 + ig * gg;
            float e = __expf(-2.0f * cv1);
            hv1 = og * (2.0f / (1.0f + e) - 1.0f);
        }
        float b0 = b2c0, b1v = b2c1;
#pragma unroll
        for (int k = 0; k < 31; k++) {
            float h1k = rdlane(hv1, k);
            float h2k = rdlane(hv2, k);
            b0 += wi2a[k] * h1k + wh2a[k] * h2k;
            b1v += wi2b[k] * h1k + wh2b[k] * h2k;
        }
        {
            float z0 = (L < 62) ? b0 : (2.0f * b0);
            float s0 = 1.0f / (1.0f + __expf(-z0));
            float act0 = (L < 62) ? s0 : (2.0f * s0 - 1.0f);
            float z1 = (L < 29) ? (2.0f * b1v) : b1v;
            float s1 = 1.0f / (1.0f + __expf(-z1));
            float act1 = (L < 29) ? (2.0f * s1 - 1.0f) : s1;
            float ig = act0;
            float fg = __shfl(act0, f_src);
            float gA = __shfl(act0, gA_src);
            float gB = __shfl(act1, gB_src);
            float gg = (L < 2) ? gA : gB;
            float og = __shfl(act1, o_src);
            cv2 = fg * cv2 + ig * gg;
            float e = __expf(-2.0f * cv2);
            hv2 = og * (2.0f / (1.0f + e) - 1.0f);
        }
        if (L < HH_) h2a[((size_t)(TT_ + s) * 64 + bb) * 32 + L] = hv2;
    }
}

// ---------------- K3: output linear for ALL 528 steps: out[b][t][:] = h2 . WT + b ----------------
__global__ __launch_bounds__(256) void k3_outlin(
    const float* __restrict__ h2a,   // [528*64][32]
    const float* __restrict__ WT,    // [31][1024]
    const float* __restrict__ blin,  // [1024]
    float* __restrict__ out)         // [B][528][1024] fp32
{
    __shared__ __align__(16) float hl[16][32];
    const int tid = threadIdx.x;
    const int m0  = blockIdx.x * 16;
#pragma unroll
    for (int p = 0; p < 2; p++) {
        int i = tid + p * 256;
        int r = i >> 5, k = i & 31;
        hl[r][k] = h2a[(size_t)(m0 + r) * 32 + k];
    }
    __syncthreads();
    const int c0 = tid * 4;
    float4 bl = *(const float4*)(blin + c0);
    float4 acc[16];
#pragma unroll
    for (int r = 0; r < 16; r++) acc[r] = bl;
    for (int k = 0; k < 31; k++) {
        float4 wv = *(const float4*)(WT + k * 1024 + c0);
#pragma unroll
        for (int r = 0; r < 16; r++) {
            float h = hl[r][k];
            acc[r].x += h * wv.x; acc[r].y += h * wv.y;
            acc[r].z += h * wv.z; acc[r].w += h * wv.w;
        }
    }
    const int t  = m0 >> 6;
    const int b0 = m0 & 63;
#pragma unroll
    for (int r = 0; r < 16; r++) {
        int b = b0 + r;
        *(float4*)(out + (size_t)b * OUT_ROW_ + (size_t)t * FF_ + c0) = acc[r];
    }
}

extern "C" void kernel_launch(void* const* d_in, const int* in_sizes, int n_in,
                              void* d_out, int out_size, void* d_ws, size_t ws_size,
                              hipStream_t stream) {
    (void)in_sizes; (void)n_in; (void)out_size; (void)ws_size;
    const float* X    = (const float*)d_in[0];
    const float* Wih1 = (const float*)d_in[1];
    const float* Whh1 = (const float*)d_in[2];
    const float* bih1 = (const float*)d_in[3];
    const float* bhh1 = (const float*)d_in[4];
    const float* Wih2 = (const float*)d_in[5];
    const float* Whh2 = (const float*)d_in[6];
    const float* bih2 = (const float*)d_in[7];
    const float* bhh2 = (const float*)d_in[8];
    const float* Wlin = (const float*)d_in[9];
    const float* blin = (const float*)d_in[10];
    // d_in[11] = future = 16 (constant for this problem)

    float* ws   = (float*)d_ws;
    float* pre1 = ws + PRE1_OFF;
    float* h2a  = ws + H2A_OFF;
    float* WT   = ws + WT_OFF;
    float* Mv   = ws + MV_OFF;
    float* out  = (float*)d_out;

    hipLaunchKernelGGL(k0_prep,    dim3(124),  dim3(256), 0, stream, Wlin, WT);
    hipLaunchKernelGGL(k0b_mv,     dim3(62),   dim3(64),  0, stream, Wih1, Wlin, blin, Mv);
    hipLaunchKernelGGL(k1_pregate, dim3(TT_),  dim3(256), 0, stream, X, Wih1, bih1, bhh1, pre1);
    hipLaunchKernelGGL(k2_recur,   dim3(BB_),  dim3(64),  0, stream, pre1, Whh1, Wih2, Whh2,
                       bih1, bhh1, bih2, bhh2, Mv, h2a);
    hipLaunchKernelGGL(k3_outlin,  dim3(TTOT_*4), dim3(256), 0, stream, h2a, WT, blin, out);
}